// Round 1
// baseline (4012.489 us; speedup 1.0000x reference)
//
#include <hip/hip_runtime.h>

// ---------------------------------------------------------------------------
// T5GNNAdapt: LN -> RGCN scatter-mean (2 relations) -> [h0|h1|x] @ [W0;W1;root]
//             + bias -> relu -> @wo -> + residual
// Shapes: B=8,S=1024,D=1024,F=4096,E=262144,N=B*S=8192, K_cat=3072
// ---------------------------------------------------------------------------

typedef unsigned short u16;
typedef unsigned int   u32;
typedef __attribute__((ext_vector_type(8))) short bf16x8;
typedef __attribute__((ext_vector_type(4))) float f32x4;

#define E_NUM  262144
#define NNODE  8192
#define DDIM   1024
#define FDIM   4096
#define KCAT   3072
#define LN_EPS 1e-6f

struct alignas(8) u16x4 { u16 x, y, z, w; };

__device__ __forceinline__ u16 f2bf(float f) {
  u32 u = __float_as_uint(f);
  u32 r = u + 0x7fffu + ((u >> 16) & 1u);   // RNE
  return (u16)(r >> 16);
}
__device__ __forceinline__ float bf2f(u16 h) {
  return __uint_as_float(((u32)h) << 16);
}

// 16-byte global -> LDS async copy (wave-uniform LDS base + lane*16 layout)
#define GLD16(gp, lp)                                              \
  __builtin_amdgcn_global_load_lds(                                \
      (__attribute__((address_space(1))) u32*)(gp),                \
      (__attribute__((address_space(3))) u32*)(lp), 16, 0, 0)

// ---------------------------------------------------------------------------
// K1: LayerNorm. One block per row; writes bf16 x into hcat[:, 2048:3072].
// ---------------------------------------------------------------------------
__global__ void ln_kernel(const float* __restrict__ hs,
                          const float* __restrict__ gamma,
                          const float* __restrict__ beta,
                          u16* __restrict__ hcat) {
  const int row = blockIdx.x;
  const int tid = threadIdx.x;
  const float4 v = ((const float4*)(hs + (size_t)row * DDIM))[tid];

  __shared__ float red[256];
  float s = v.x + v.y + v.z + v.w;
  red[tid] = s;
  __syncthreads();
  for (int st = 128; st > 0; st >>= 1) {
    if (tid < st) red[tid] += red[tid + st];
    __syncthreads();
  }
  const float mean = red[0] * (1.0f / DDIM);
  __syncthreads();

  const float dx = v.x - mean, dy = v.y - mean, dz = v.z - mean, dw = v.w - mean;
  red[tid] = dx * dx + dy * dy + dz * dz + dw * dw;
  __syncthreads();
  for (int st = 128; st > 0; st >>= 1) {
    if (tid < st) red[tid] += red[tid + st];
    __syncthreads();
  }
  const float var = red[0] * (1.0f / DDIM);
  const float rs  = rsqrtf(var + LN_EPS);

  const int base = tid * 4;
  const float4 g = *(const float4*)(gamma + base);
  const float4 b = *(const float4*)(beta + base);
  u16x4 o;
  o.x = f2bf(dx * rs * g.x + b.x);
  o.y = f2bf(dy * rs * g.y + b.y);
  o.z = f2bf(dz * rs * g.z + b.z);
  o.w = f2bf(dw * rs * g.w + b.w);
  *(u16x4*)(hcat + (size_t)row * KCAT + 2048 + base) = o;
}

// ---------------------------------------------------------------------------
// K2: f32 [K,N] -> bf16 [N,K] transpose (stitches two sources along K).
// block (32,8), grid (N/32, K/32)
// ---------------------------------------------------------------------------
__global__ void cvt_transpose(const float* __restrict__ srcA,
                              const float* __restrict__ srcB,
                              int splitK, int K, int N,
                              u16* __restrict__ dst) {
  __shared__ float tile[32][33];
  const int n0 = blockIdx.x * 32, k0 = blockIdx.y * 32;
  const int tx = threadIdx.x, ty = threadIdx.y;
  for (int i = ty; i < 32; i += 8) {
    const int k = k0 + i;
    const float v = (k < splitK) ? srcA[(size_t)k * N + n0 + tx]
                                 : srcB[(size_t)(k - splitK) * N + n0 + tx];
    tile[i][tx] = v;
  }
  __syncthreads();
  for (int i = ty; i < 32; i += 8) {
    dst[(size_t)(n0 + i) * K + k0 + tx] = f2bf(tile[tx][i]);
  }
}

// ---------------------------------------------------------------------------
// K3: edge scatter-add. One block (256 thr) per edge: 4 f32 atomics/thread.
// ---------------------------------------------------------------------------
__global__ void edge_scatter(const int* __restrict__ edge_index,
                             const int* __restrict__ edge_type,
                             const u16* __restrict__ hcat,
                             float* __restrict__ agg,
                             float* __restrict__ cnt) {
  const int e = blockIdx.x;
  const int s = edge_index[e];
  const int d = edge_index[E_NUM + e];
  const int r = edge_type[e];
  const int tid = threadIdx.x;

  const uint2 raw = *(const uint2*)(hcat + (size_t)s * KCAT + 2048 + tid * 4);
  float* ad = agg + ((size_t)r * NNODE + d) * DDIM + tid * 4;
  atomicAdd(ad + 0, bf2f((u16)(raw.x & 0xffffu)));
  atomicAdd(ad + 1, bf2f((u16)(raw.x >> 16)));
  atomicAdd(ad + 2, bf2f((u16)(raw.y & 0xffffu)));
  atomicAdd(ad + 3, bf2f((u16)(raw.y >> 16)));
  if (tid == 0) atomicAdd(cnt + r * NNODE + d, 1.0f);
}

// ---------------------------------------------------------------------------
// K4: h = agg / max(cnt,1) -> bf16 into hcat[:, r*1024 : (r+1)*1024]
// grid 2*NNODE blocks of 256
// ---------------------------------------------------------------------------
__global__ void finalize_h(const float* __restrict__ agg,
                           const float* __restrict__ cnt,
                           u16* __restrict__ hcat) {
  const int b = blockIdx.x;          // r*NNODE + node
  const int r = b >> 13, node = b & (NNODE - 1);
  const int tid = threadIdx.x;
  const float inv = 1.0f / fmaxf(cnt[b], 1.0f);
  const float4 v = *(const float4*)(agg + (size_t)b * DDIM + tid * 4);
  u16x4 o;
  o.x = f2bf(v.x * inv);
  o.y = f2bf(v.y * inv);
  o.z = f2bf(v.z * inv);
  o.w = f2bf(v.w * inv);
  *(u16x4*)(hcat + (size_t)node * KCAT + (size_t)r * DDIM + tid * 4) = o;
}

// ---------------------------------------------------------------------------
// GEMM: C[M,N] = A[M,K] @ Bt[N,K]^T   (both bf16, fp32 accum)
// m97 structure: 128x128 tile, BK=32, 4 waves of 4x4 16x16x32 MFMAs,
// global_load_lds width=16 staging.
// EPI=0: out = bf16(relu(C + bias[col]))        -> obf
// EPI=1: out = f32(C + resid)                   -> of32
// ---------------------------------------------------------------------------
template <int EPI>
__global__ __launch_bounds__(256) void gemm_bt(
    const u16* __restrict__ A, const u16* __restrict__ Bt,
    int M, int N, int K,
    const float* __restrict__ bias, const float* __restrict__ resid,
    u16* __restrict__ obf, float* __restrict__ of32) {
  __shared__ __align__(16) u16 sA[128 * 32];
  __shared__ __align__(16) u16 sB[128 * 32];
  const int tid  = threadIdx.x;
  const int lane = tid & 63;
  const int wave = tid >> 6;
  const int bm = blockIdx.x * 128;
  const int bn = blockIdx.y * 128;
  const int wm = (wave >> 1) * 64;
  const int wn = (wave & 1) * 64;
  const int lr   = lane & 15;
  const int quad = lane >> 4;

  f32x4 acc[4][4] = {};

  // staging: 512 16B chunks per tile, 2 per thread; chunk c -> (row=c>>2, seg=c&3)
  const int c0 = tid, c1 = tid + 256;
  const u16* gA0 = A  + (size_t)(bm + (c0 >> 2)) * K + (c0 & 3) * 8;
  const u16* gA1 = A  + (size_t)(bm + (c1 >> 2)) * K + (c1 & 3) * 8;
  const u16* gB0 = Bt + (size_t)(bn + (c0 >> 2)) * K + (c0 & 3) * 8;
  const u16* gB1 = Bt + (size_t)(bn + (c1 >> 2)) * K + (c1 & 3) * 8;
  u16* lA0 = sA + c0 * 8;
  u16* lA1 = sA + c1 * 8;
  u16* lB0 = sB + c0 * 8;
  u16* lB1 = sB + c1 * 8;

  for (int k0 = 0; k0 < K; k0 += 32) {
    GLD16(gA0 + k0, lA0);
    GLD16(gA1 + k0, lA1);
    GLD16(gB0 + k0, lB0);
    GLD16(gB1 + k0, lB1);
    __syncthreads();   // drains vmcnt before use

    const bf16x8* pA = (const bf16x8*)sA;
    const bf16x8* pB = (const bf16x8*)sB;
    bf16x8 av[4], bv[4];
#pragma unroll
    for (int mi = 0; mi < 4; ++mi) av[mi] = pA[(wm + mi * 16 + lr) * 4 + quad];
#pragma unroll
    for (int ni = 0; ni < 4; ++ni) bv[ni] = pB[(wn + ni * 16 + lr) * 4 + quad];
#pragma unroll
    for (int mi = 0; mi < 4; ++mi)
#pragma unroll
      for (int ni = 0; ni < 4; ++ni)
        acc[mi][ni] = __builtin_amdgcn_mfma_f32_16x16x32_bf16(
            av[mi], bv[ni], acc[mi][ni], 0, 0, 0);
    __syncthreads();   // protect LDS before next stage
  }

  // epilogue: C/D layout col=lane&15, row=quad*4+reg (verified m89/m91)
#pragma unroll
  for (int mi = 0; mi < 4; ++mi) {
#pragma unroll
    for (int ni = 0; ni < 4; ++ni) {
      const int col  = bn + wn + ni * 16 + lr;
      const int row0 = bm + wm + mi * 16 + quad * 4;
      if constexpr (EPI == 0) {
        const float bb = bias[col];
#pragma unroll
        for (int r = 0; r < 4; ++r) {
          float v = acc[mi][ni][r] + bb;
          v = fmaxf(v, 0.0f);
          obf[(size_t)(row0 + r) * N + col] = f2bf(v);
        }
      } else {
#pragma unroll
        for (int r = 0; r < 4; ++r) {
          const size_t idx = (size_t)(row0 + r) * N + col;
          of32[idx] = resid[idx] + acc[mi][ni][r];
        }
      }
    }
  }
}

// ---------------------------------------------------------------------------
// Workspace layout (bytes):
//   hcat   [8192 x 3072] bf16                  @ 0          (50331648)
//   WcatT  [4096 x 3072] bf16                  @ 50331648   (25165824)
//   woT    [1024 x 4096] bf16                  @ 75497472   ( 8388608)
//   agg    [2 x 8192 x 1024] f32  (= out1 bf16 alias)
//                                              @ 83886080   (67108864)
//   cnt    [2 x 8192] f32                      @ 150994944  (   65536)
// total: 151060480 bytes (~144 MB)
// ---------------------------------------------------------------------------
extern "C" void kernel_launch(void* const* d_in, const int* in_sizes, int n_in,
                              void* d_out, int out_size, void* d_ws, size_t ws_size,
                              hipStream_t stream) {
  const float* hs     = (const float*)d_in[0];
  const float* weight = (const float*)d_in[1];   // [2,1024,4096]
  const float* root   = (const float*)d_in[2];   // [1024,4096]
  const float* bias   = (const float*)d_in[3];   // [4096]
  const float* wo     = (const float*)d_in[4];   // [4096,1024]
  const float* gamma  = (const float*)d_in[5];
  const float* beta   = (const float*)d_in[6];
  const int* edge_index = (const int*)d_in[7];   // [2,E]
  const int* edge_type  = (const int*)d_in[8];   // [E]
  float* out = (float*)d_out;

  char* ws = (char*)d_ws;
  u16*   hcat  = (u16*)(ws + 0);
  u16*   WcatT = (u16*)(ws + 50331648);
  u16*   woT   = (u16*)(ws + 75497472);
  float* agg   = (float*)(ws + 83886080);
  u16*   out1  = (u16*)(ws + 83886080);          // aliases agg (safe: agg consumed first)
  float* cnt   = (float*)(ws + 150994944);

  // zero the scatter accumulators (+ counts)
  (void)hipMemsetAsync(agg, 0, 67108864 + 65536, stream);

  ln_kernel<<<NNODE, 256, 0, stream>>>(hs, gamma, beta, hcat);

  // [W0;W1;root] -> bf16 [4096,3072]   and   wo -> bf16 [1024,4096]
  cvt_transpose<<<dim3(FDIM / 32, KCAT / 32), dim3(32, 8), 0, stream>>>(
      weight, root, 2048, KCAT, FDIM, WcatT);
  cvt_transpose<<<dim3(DDIM / 32, FDIM / 32), dim3(32, 8), 0, stream>>>(
      wo, wo, FDIM, FDIM, DDIM, woT);

  edge_scatter<<<E_NUM, 256, 0, stream>>>(edge_index, edge_type, hcat, agg, cnt);
  finalize_h<<<2 * NNODE, 256, 0, stream>>>(agg, cnt, hcat);

  // out1 = relu([h0|h1|x] @ [W0;W1;root] + bias)   [8192 x 4096] bf16
  gemm_bt<0><<<dim3(8192 / 128, FDIM / 128), 256, 0, stream>>>(
      hcat, WcatT, 8192, FDIM, KCAT, bias, nullptr, out1, nullptr);

  // out = hs + out1 @ wo                            [8192 x 1024] f32
  gemm_bt<1><<<dim3(8192 / 128, DDIM / 128), 256, 0, stream>>>(
      out1, woT, 8192, DDIM, FDIM, nullptr, hs, nullptr, out);
}

// Round 2
// 621.116 us; speedup vs baseline: 6.4601x; 6.4601x over previous
//
#include <hip/hip_runtime.h>

// ---------------------------------------------------------------------------
// T5GNNAdapt: LN -> RGCN scatter-mean (2 relations) -> [h0|h1|x] @ [W0;W1;root]
//             + bias -> relu -> @wo -> + residual
// Shapes: B=8,S=1024,D=1024,F=4096,E=262144,N=B*S=8192, K_cat=3072
// R1->R2: replaced f32-atomic edge_scatter (3425us, 4.2GB atomic WRITE) with
// CSR bucket sort + per-node register aggregation (no feature atomics).
// ---------------------------------------------------------------------------

typedef unsigned short u16;
typedef unsigned int   u32;
typedef __attribute__((ext_vector_type(8))) short bf16x8;
typedef __attribute__((ext_vector_type(4))) float f32x4;

#define E_NUM  262144
#define NNODE  8192
#define NBKT   (2 * NNODE)      // 16384 (rel,dst) buckets
#define DDIM   1024
#define FDIM   4096
#define KCAT   3072
#define LN_EPS 1e-6f

struct alignas(8) u16x4 { u16 x, y, z, w; };

__device__ __forceinline__ u16 f2bf(float f) {
  u32 u = __float_as_uint(f);
  u32 r = u + 0x7fffu + ((u >> 16) & 1u);   // RNE
  return (u16)(r >> 16);
}
__device__ __forceinline__ float bf2f(u16 h) {
  return __uint_as_float(((u32)h) << 16);
}

// 16-byte global -> LDS async copy (wave-uniform LDS base + lane*16 layout)
#define GLD16(gp, lp)                                              \
  __builtin_amdgcn_global_load_lds(                                \
      (__attribute__((address_space(1))) u32*)(gp),                \
      (__attribute__((address_space(3))) u32*)(lp), 16, 0, 0)

// ---------------------------------------------------------------------------
// K1: LayerNorm. One block per row; writes bf16 x into hcat[:, 2048:3072].
// ---------------------------------------------------------------------------
__global__ void ln_kernel(const float* __restrict__ hs,
                          const float* __restrict__ gamma,
                          const float* __restrict__ beta,
                          u16* __restrict__ hcat) {
  const int row = blockIdx.x;
  const int tid = threadIdx.x;
  const float4 v = ((const float4*)(hs + (size_t)row * DDIM))[tid];

  __shared__ float red[256];
  float s = v.x + v.y + v.z + v.w;
  red[tid] = s;
  __syncthreads();
  for (int st = 128; st > 0; st >>= 1) {
    if (tid < st) red[tid] += red[tid + st];
    __syncthreads();
  }
  const float mean = red[0] * (1.0f / DDIM);
  __syncthreads();

  const float dx = v.x - mean, dy = v.y - mean, dz = v.z - mean, dw = v.w - mean;
  red[tid] = dx * dx + dy * dy + dz * dz + dw * dw;
  __syncthreads();
  for (int st = 128; st > 0; st >>= 1) {
    if (tid < st) red[tid] += red[tid + st];
    __syncthreads();
  }
  const float var = red[0] * (1.0f / DDIM);
  const float rs  = rsqrtf(var + LN_EPS);

  const int base = tid * 4;
  const float4 g = *(const float4*)(gamma + base);
  const float4 b = *(const float4*)(beta + base);
  u16x4 o;
  o.x = f2bf(dx * rs * g.x + b.x);
  o.y = f2bf(dy * rs * g.y + b.y);
  o.z = f2bf(dz * rs * g.z + b.z);
  o.w = f2bf(dw * rs * g.w + b.w);
  *(u16x4*)(hcat + (size_t)row * KCAT + 2048 + base) = o;
}

// ---------------------------------------------------------------------------
// K2: f32 [K,N] -> bf16 [N,K] transpose (stitches two sources along K).
// ---------------------------------------------------------------------------
__global__ void cvt_transpose(const float* __restrict__ srcA,
                              const float* __restrict__ srcB,
                              int splitK, int K, int N,
                              u16* __restrict__ dst) {
  __shared__ float tile[32][33];
  const int n0 = blockIdx.x * 32, k0 = blockIdx.y * 32;
  const int tx = threadIdx.x, ty = threadIdx.y;
  for (int i = ty; i < 32; i += 8) {
    const int k = k0 + i;
    const float v = (k < splitK) ? srcA[(size_t)k * N + n0 + tx]
                                 : srcB[(size_t)(k - splitK) * N + n0 + tx];
    tile[i][tx] = v;
  }
  __syncthreads();
  for (int i = ty; i < 32; i += 8) {
    dst[(size_t)(n0 + i) * K + k0 + tx] = f2bf(tile[tx][i]);
  }
}

// ---------------------------------------------------------------------------
// K3a: count edges per (rel,dst) bucket.
// ---------------------------------------------------------------------------
__global__ void count_kernel(const int* __restrict__ edge_index,
                             const int* __restrict__ edge_type,
                             int* __restrict__ cnt) {
  const int e = blockIdx.x * 256 + threadIdx.x;
  const int d = edge_index[E_NUM + e];
  const int r = edge_type[e];
  atomicAdd(&cnt[r * NNODE + d], 1);
}

// ---------------------------------------------------------------------------
// K3b: exclusive prefix sum over 16384 counts (single block, 1024 thr).
// ---------------------------------------------------------------------------
__global__ __launch_bounds__(1024) void scan_kernel(const int* __restrict__ cnt,
                                                    int* __restrict__ off,
                                                    int* __restrict__ cursor) {
  __shared__ int partial[1024];
  const int tid  = threadIdx.x;
  const int base = tid * 16;
  int local[16];
  int s = 0;
#pragma unroll
  for (int i = 0; i < 16; ++i) { local[i] = s; s += cnt[base + i]; }
  partial[tid] = s;
  __syncthreads();
  for (int st = 1; st < 1024; st <<= 1) {
    const int v = (tid >= st) ? partial[tid - st] : 0;
    __syncthreads();
    partial[tid] += v;
    __syncthreads();
  }
  const int pre = (tid == 0) ? 0 : partial[tid - 1];
#pragma unroll
  for (int i = 0; i < 16; ++i) {
    const int o = pre + local[i];
    off[base + i]    = o;
    cursor[base + i] = o;
  }
}

// ---------------------------------------------------------------------------
// K3c: scatter edge SOURCE ids into buckets (4B per edge, not 4KB rows).
// ---------------------------------------------------------------------------
__global__ void fill_kernel(const int* __restrict__ edge_index,
                            const int* __restrict__ edge_type,
                            int* __restrict__ cursor,
                            int* __restrict__ bucket_src) {
  const int e = blockIdx.x * 256 + threadIdx.x;
  const int s = edge_index[e];
  const int d = edge_index[E_NUM + e];
  const int r = edge_type[e];
  const int pos = atomicAdd(&cursor[r * NNODE + d], 1);
  bucket_src[pos] = s;
}

// ---------------------------------------------------------------------------
// K4: per-(rel,node) aggregation. Gather bf16 x-rows via LDS-staged id list,
// accumulate f32 in registers, write mean as bf16 into hcat. No atomics.
// ---------------------------------------------------------------------------
__global__ __launch_bounds__(256) void aggregate_kernel(
    const int* __restrict__ cnt, const int* __restrict__ off,
    const int* __restrict__ bucket_src, u16* __restrict__ hcat) {
  const int b    = blockIdx.x;            // r*NNODE + node
  const int r    = b >> 13;
  const int node = b & (NNODE - 1);
  const int tid  = threadIdx.x;
  const int n     = cnt[b];
  const int start = off[b];

  __shared__ int ids[512];
  float a0 = 0.f, a1 = 0.f, a2 = 0.f, a3 = 0.f;

  for (int c0 = 0; c0 < n; c0 += 512) {
    const int m = min(n - c0, 512);
    __syncthreads();
    for (int i = tid; i < m; i += 256) ids[i] = bucket_src[start + c0 + i];
    __syncthreads();
    for (int j = 0; j < m; ++j) {
      const int s = ids[j];   // broadcast read
      const uint2 raw = *(const uint2*)(hcat + (size_t)s * KCAT + 2048 + tid * 4);
      a0 += bf2f((u16)(raw.x & 0xffffu));
      a1 += bf2f((u16)(raw.x >> 16));
      a2 += bf2f((u16)(raw.y & 0xffffu));
      a3 += bf2f((u16)(raw.y >> 16));
    }
  }

  const float inv = 1.0f / fmaxf((float)n, 1.0f);
  u16x4 o;
  o.x = f2bf(a0 * inv);
  o.y = f2bf(a1 * inv);
  o.z = f2bf(a2 * inv);
  o.w = f2bf(a3 * inv);
  *(u16x4*)(hcat + (size_t)node * KCAT + (size_t)r * DDIM + tid * 4) = o;
}

// ---------------------------------------------------------------------------
// GEMM: C[M,N] = A[M,K] @ Bt[N,K]^T   (both bf16, fp32 accum), m97 structure.
// EPI=0: out = bf16(relu(C + bias[col]))        -> obf
// EPI=1: out = f32(C + resid)                   -> of32
// ---------------------------------------------------------------------------
template <int EPI>
__global__ __launch_bounds__(256) void gemm_bt(
    const u16* __restrict__ A, const u16* __restrict__ Bt,
    int M, int N, int K,
    const float* __restrict__ bias, const float* __restrict__ resid,
    u16* __restrict__ obf, float* __restrict__ of32) {
  __shared__ __align__(16) u16 sA[128 * 32];
  __shared__ __align__(16) u16 sB[128 * 32];
  const int tid  = threadIdx.x;
  const int lane = tid & 63;
  const int wave = tid >> 6;
  const int bm = blockIdx.x * 128;
  const int bn = blockIdx.y * 128;
  const int wm = (wave >> 1) * 64;
  const int wn = (wave & 1) * 64;
  const int lr   = lane & 15;
  const int quad = lane >> 4;

  f32x4 acc[4][4] = {};

  const int c0 = tid, c1 = tid + 256;
  const u16* gA0 = A  + (size_t)(bm + (c0 >> 2)) * K + (c0 & 3) * 8;
  const u16* gA1 = A  + (size_t)(bm + (c1 >> 2)) * K + (c1 & 3) * 8;
  const u16* gB0 = Bt + (size_t)(bn + (c0 >> 2)) * K + (c0 & 3) * 8;
  const u16* gB1 = Bt + (size_t)(bn + (c1 >> 2)) * K + (c1 & 3) * 8;
  u16* lA0 = sA + c0 * 8;
  u16* lA1 = sA + c1 * 8;
  u16* lB0 = sB + c0 * 8;
  u16* lB1 = sB + c1 * 8;

  for (int k0 = 0; k0 < K; k0 += 32) {
    GLD16(gA0 + k0, lA0);
    GLD16(gA1 + k0, lA1);
    GLD16(gB0 + k0, lB0);
    GLD16(gB1 + k0, lB1);
    __syncthreads();

    const bf16x8* pA = (const bf16x8*)sA;
    const bf16x8* pB = (const bf16x8*)sB;
    bf16x8 av[4], bv[4];
#pragma unroll
    for (int mi = 0; mi < 4; ++mi) av[mi] = pA[(wm + mi * 16 + lr) * 4 + quad];
#pragma unroll
    for (int ni = 0; ni < 4; ++ni) bv[ni] = pB[(wn + ni * 16 + lr) * 4 + quad];
#pragma unroll
    for (int mi = 0; mi < 4; ++mi)
#pragma unroll
      for (int ni = 0; ni < 4; ++ni)
        acc[mi][ni] = __builtin_amdgcn_mfma_f32_16x16x32_bf16(
            av[mi], bv[ni], acc[mi][ni], 0, 0, 0);
    __syncthreads();
  }

#pragma unroll
  for (int mi = 0; mi < 4; ++mi) {
#pragma unroll
    for (int ni = 0; ni < 4; ++ni) {
      const int col  = bn + wn + ni * 16 + lr;
      const int row0 = bm + wm + mi * 16 + quad * 4;
      if constexpr (EPI == 0) {
        const float bb = bias[col];
#pragma unroll
        for (int r = 0; r < 4; ++r) {
          float v = acc[mi][ni][r] + bb;
          v = fmaxf(v, 0.0f);
          obf[(size_t)(row0 + r) * N + col] = f2bf(v);
        }
      } else {
#pragma unroll
        for (int r = 0; r < 4; ++r) {
          const size_t idx = (size_t)(row0 + r) * N + col;
          of32[idx] = resid[idx] + acc[mi][ni][r];
        }
      }
    }
  }
}

// ---------------------------------------------------------------------------
// Workspace layout (bytes):
//   hcat       [8192 x 3072] bf16              @ 0          (50331648)
//   WcatT      [4096 x 3072] bf16              @ 50331648   (25165824)
//   woT        [1024 x 4096] bf16              @ 75497472   ( 8388608)
//   out1       [8192 x 4096] bf16              @ 83886080   (67108864)
//     bucket_src [262144] i32 (aliases out1)   @ 83886080   ( 1048576)
//     cnt        [16384] i32                   @ 84934656   (   65536)
//     off        [16384] i32                   @ 85000192   (   65536)
//     cursor     [16384] i32                   @ 85065728   (   65536)
// total: 150994944 bytes (144 MB) — within round-1 footprint.
// ---------------------------------------------------------------------------
extern "C" void kernel_launch(void* const* d_in, const int* in_sizes, int n_in,
                              void* d_out, int out_size, void* d_ws, size_t ws_size,
                              hipStream_t stream) {
  const float* hs     = (const float*)d_in[0];
  const float* weight = (const float*)d_in[1];   // [2,1024,4096]
  const float* root   = (const float*)d_in[2];   // [1024,4096]
  const float* bias   = (const float*)d_in[3];   // [4096]
  const float* wo     = (const float*)d_in[4];   // [4096,1024]
  const float* gamma  = (const float*)d_in[5];
  const float* beta   = (const float*)d_in[6];
  const int* edge_index = (const int*)d_in[7];   // [2,E]
  const int* edge_type  = (const int*)d_in[8];   // [E]
  float* out = (float*)d_out;

  char* ws = (char*)d_ws;
  u16*   hcat       = (u16*)(ws + 0);
  u16*   WcatT      = (u16*)(ws + 50331648);
  u16*   woT        = (u16*)(ws + 75497472);
  u16*   out1       = (u16*)(ws + 83886080);
  int*   bucket_src = (int*)(ws + 83886080);     // aliases out1 (consumed pre-GEMM1)
  int*   cnt        = (int*)(ws + 84934656);
  int*   off        = (int*)(ws + 85000192);
  int*   cursor     = (int*)(ws + 85065728);

  (void)hipMemsetAsync(cnt, 0, 65536, stream);

  ln_kernel<<<NNODE, 256, 0, stream>>>(hs, gamma, beta, hcat);

  cvt_transpose<<<dim3(FDIM / 32, KCAT / 32), dim3(32, 8), 0, stream>>>(
      weight, root, 2048, KCAT, FDIM, WcatT);
  cvt_transpose<<<dim3(DDIM / 32, FDIM / 32), dim3(32, 8), 0, stream>>>(
      wo, wo, FDIM, FDIM, DDIM, woT);

  count_kernel<<<E_NUM / 256, 256, 0, stream>>>(edge_index, edge_type, cnt);
  scan_kernel<<<1, 1024, 0, stream>>>(cnt, off, cursor);
  fill_kernel<<<E_NUM / 256, 256, 0, stream>>>(edge_index, edge_type, cursor, bucket_src);
  aggregate_kernel<<<NBKT, 256, 0, stream>>>(cnt, off, bucket_src, hcat);

  // out1 = relu([h0|h1|x] @ [W0;W1;root] + bias)   [8192 x 4096] bf16
  gemm_bt<0><<<dim3(8192 / 128, FDIM / 128), 256, 0, stream>>>(
      hcat, WcatT, 8192, FDIM, KCAT, bias, nullptr, out1, nullptr);

  // out = hs + out1 @ wo                            [8192 x 1024] f32
  gemm_bt<1><<<dim3(8192 / 128, DDIM / 128), 256, 0, stream>>>(
      out1, woT, 8192, DDIM, FDIM, nullptr, hs, nullptr, out);
}

// Round 3
// 548.508 us; speedup vs baseline: 7.3153x; 1.1324x over previous
//
#include <hip/hip_runtime.h>

// ---------------------------------------------------------------------------
// T5GNNAdapt: LN -> RGCN scatter-mean (2 relations) -> [h0|h1|x] @ [W0;W1;root]
//             + bias -> relu -> @wo -> + residual
// Shapes: B=8,S=1024,D=1024,F=4096,E=262144,N=B*S=8192, K_cat=3072
// R2->R3: GEMM BK=64 + XOR-swizzled LDS (kills 8-deep bank conflicts that
// global_load_lds's fixed lane->LDS mapping otherwise forces); aggregate
// uses 16B gathers with 2 edges/iter + LDS cross-half reduce; LN one-pass.
// ---------------------------------------------------------------------------

typedef unsigned short u16;
typedef unsigned int   u32;
typedef __attribute__((ext_vector_type(8))) short bf16x8;
typedef __attribute__((ext_vector_type(4))) float f32x4;

#define E_NUM  262144
#define NNODE  8192
#define NBKT   (2 * NNODE)      // 16384 (rel,dst) buckets
#define DDIM   1024
#define FDIM   4096
#define KCAT   3072
#define LN_EPS 1e-6f

struct alignas(8) u16x4 { u16 x, y, z, w; };

__device__ __forceinline__ u16 f2bf(float f) {
  u32 u = __float_as_uint(f);
  u32 r = u + 0x7fffu + ((u >> 16) & 1u);   // RNE
  return (u16)(r >> 16);
}
__device__ __forceinline__ float bf2f(u16 h) {
  return __uint_as_float(((u32)h) << 16);
}

// 16-byte global -> LDS async copy (wave-uniform LDS base + lane*16 layout)
#define GLD16(gp, lp)                                              \
  __builtin_amdgcn_global_load_lds(                                \
      (__attribute__((address_space(1))) u32*)(gp),                \
      (__attribute__((address_space(3))) u32*)(lp), 16, 0, 0)

// ---------------------------------------------------------------------------
// K1: LayerNorm (one-pass sum/sumsq). One block per row; writes bf16 x into
// hcat[:, 2048:3072].
// ---------------------------------------------------------------------------
__global__ void ln_kernel(const float* __restrict__ hs,
                          const float* __restrict__ gamma,
                          const float* __restrict__ beta,
                          u16* __restrict__ hcat) {
  const int row = blockIdx.x;
  const int tid = threadIdx.x;
  const float4 v = ((const float4*)(hs + (size_t)row * DDIM))[tid];

  __shared__ float r1[256], r2[256];
  r1[tid] = v.x + v.y + v.z + v.w;
  r2[tid] = v.x * v.x + v.y * v.y + v.z * v.z + v.w * v.w;
  __syncthreads();
  for (int st = 128; st > 0; st >>= 1) {
    if (tid < st) { r1[tid] += r1[tid + st]; r2[tid] += r2[tid + st]; }
    __syncthreads();
  }
  const float mean = r1[0] * (1.0f / DDIM);
  const float var  = r2[0] * (1.0f / DDIM) - mean * mean;
  const float rs   = rsqrtf(var + LN_EPS);

  const int base = tid * 4;
  const float4 g = *(const float4*)(gamma + base);
  const float4 b = *(const float4*)(beta + base);
  u16x4 o;
  o.x = f2bf((v.x - mean) * rs * g.x + b.x);
  o.y = f2bf((v.y - mean) * rs * g.y + b.y);
  o.z = f2bf((v.z - mean) * rs * g.z + b.z);
  o.w = f2bf((v.w - mean) * rs * g.w + b.w);
  *(u16x4*)(hcat + (size_t)row * KCAT + 2048 + base) = o;
}

// ---------------------------------------------------------------------------
// K2: f32 [K,N] -> bf16 [N,K] transpose (stitches two sources along K).
// ---------------------------------------------------------------------------
__global__ void cvt_transpose(const float* __restrict__ srcA,
                              const float* __restrict__ srcB,
                              int splitK, int K, int N,
                              u16* __restrict__ dst) {
  __shared__ float tile[32][33];
  const int n0 = blockIdx.x * 32, k0 = blockIdx.y * 32;
  const int tx = threadIdx.x, ty = threadIdx.y;
  for (int i = ty; i < 32; i += 8) {
    const int k = k0 + i;
    const float v = (k < splitK) ? srcA[(size_t)k * N + n0 + tx]
                                 : srcB[(size_t)(k - splitK) * N + n0 + tx];
    tile[i][tx] = v;
  }
  __syncthreads();
  for (int i = ty; i < 32; i += 8) {
    dst[(size_t)(n0 + i) * K + k0 + tx] = f2bf(tile[tx][i]);
  }
}

// ---------------------------------------------------------------------------
// K3a: count edges per (rel,dst) bucket.
// ---------------------------------------------------------------------------
__global__ void count_kernel(const int* __restrict__ edge_index,
                             const int* __restrict__ edge_type,
                             int* __restrict__ cnt) {
  const int e = blockIdx.x * 256 + threadIdx.x;
  const int d = edge_index[E_NUM + e];
  const int r = edge_type[e];
  atomicAdd(&cnt[r * NNODE + d], 1);
}

// ---------------------------------------------------------------------------
// K3b: exclusive prefix sum over 16384 counts (single block, 1024 thr).
// ---------------------------------------------------------------------------
__global__ __launch_bounds__(1024) void scan_kernel(const int* __restrict__ cnt,
                                                    int* __restrict__ off,
                                                    int* __restrict__ cursor) {
  __shared__ int partial[1024];
  const int tid  = threadIdx.x;
  const int base = tid * 16;
  int local[16];
  int s = 0;
#pragma unroll
  for (int i = 0; i < 16; ++i) { local[i] = s; s += cnt[base + i]; }
  partial[tid] = s;
  __syncthreads();
  for (int st = 1; st < 1024; st <<= 1) {
    const int v = (tid >= st) ? partial[tid - st] : 0;
    __syncthreads();
    partial[tid] += v;
    __syncthreads();
  }
  const int pre = (tid == 0) ? 0 : partial[tid - 1];
#pragma unroll
  for (int i = 0; i < 16; ++i) {
    const int o = pre + local[i];
    off[base + i]    = o;
    cursor[base + i] = o;
  }
}

// ---------------------------------------------------------------------------
// K3c: scatter edge SOURCE ids into buckets (4B per edge, not 4KB rows).
// ---------------------------------------------------------------------------
__global__ void fill_kernel(const int* __restrict__ edge_index,
                            const int* __restrict__ edge_type,
                            int* __restrict__ cursor,
                            int* __restrict__ bucket_src) {
  const int e = blockIdx.x * 256 + threadIdx.x;
  const int s = edge_index[e];
  const int d = edge_index[E_NUM + e];
  const int r = edge_type[e];
  const int pos = atomicAdd(&cursor[r * NNODE + d], 1);
  bucket_src[pos] = s;
}

// ---------------------------------------------------------------------------
// K4: per-(rel,node) aggregation. tid splits into 2 half-groups of 128;
// each half processes alternate edges with 16B uint4 gathers (8 cols/thread),
// cross-half reduce via LDS, 16B bf16 output store. No atomics.
// ---------------------------------------------------------------------------
__global__ __launch_bounds__(256) void aggregate_kernel(
    const int* __restrict__ cnt, const int* __restrict__ off,
    const int* __restrict__ bucket_src, u16* __restrict__ hcat) {
  const int b    = blockIdx.x;            // r*NNODE + node
  const int r    = b >> 13;
  const int node = b & (NNODE - 1);
  const int tid  = threadIdx.x;
  const int g    = tid >> 7;              // half-group 0/1
  const int c    = tid & 127;             // col chunk: cols c*8 .. c*8+7
  const int n     = cnt[b];
  const int start = off[b];

  __shared__ int   ids[256];
  __shared__ float red[1024];
  float a[8] = {};

  for (int c0 = 0; c0 < n; c0 += 256) {
    const int m = min(n - c0, 256);
    __syncthreads();
    if (tid < m) ids[tid] = bucket_src[start + c0 + tid];
    __syncthreads();
    for (int j = g; j < m; j += 2) {
      const int s = ids[j];   // broadcast read
      const uint4 raw = *(const uint4*)(hcat + (size_t)s * KCAT + 2048 + c * 8);
      a[0] += bf2f((u16)(raw.x & 0xffffu)); a[1] += bf2f((u16)(raw.x >> 16));
      a[2] += bf2f((u16)(raw.y & 0xffffu)); a[3] += bf2f((u16)(raw.y >> 16));
      a[4] += bf2f((u16)(raw.z & 0xffffu)); a[5] += bf2f((u16)(raw.z >> 16));
      a[6] += bf2f((u16)(raw.w & 0xffffu)); a[7] += bf2f((u16)(raw.w >> 16));
    }
  }

  if (g == 1) {
    *(float4*)&red[c * 8 + 0] = make_float4(a[0], a[1], a[2], a[3]);
    *(float4*)&red[c * 8 + 4] = make_float4(a[4], a[5], a[6], a[7]);
  }
  __syncthreads();
  if (g == 0) {
    const float4 p0 = *(const float4*)&red[c * 8 + 0];
    const float4 p1 = *(const float4*)&red[c * 8 + 4];
    a[0] += p0.x; a[1] += p0.y; a[2] += p0.z; a[3] += p0.w;
    a[4] += p1.x; a[5] += p1.y; a[6] += p1.z; a[7] += p1.w;
    const float inv = 1.0f / fmaxf((float)n, 1.0f);
    uint4 o;
    o.x = (u32)f2bf(a[0] * inv) | ((u32)f2bf(a[1] * inv) << 16);
    o.y = (u32)f2bf(a[2] * inv) | ((u32)f2bf(a[3] * inv) << 16);
    o.z = (u32)f2bf(a[4] * inv) | ((u32)f2bf(a[5] * inv) << 16);
    o.w = (u32)f2bf(a[6] * inv) | ((u32)f2bf(a[7] * inv) << 16);
    *(uint4*)(hcat + (size_t)node * KCAT + (size_t)r * DDIM + c * 8) = o;
  }
}

// ---------------------------------------------------------------------------
// GEMM: C[M,N] = A[M,K] @ Bt[N,K]^T   (both bf16, fp32 accum)
// 128x128 tile, BK=64 (48/64 iters), XOR-swizzled LDS:
//   slot (row, seg') holds global seg = seg' ^ (row & 7)   (8 segs x 16B/row)
// -> quarter-wave ds_read_b128 spreads over all 8 bank-groups 2-deep (free).
// EPI=0: out = bf16(relu(C + bias[col]))        -> obf
// EPI=1: out = f32(C + resid)                   -> of32
// ---------------------------------------------------------------------------
template <int EPI>
__global__ __launch_bounds__(256) void gemm_bt(
    const u16* __restrict__ A, const u16* __restrict__ Bt,
    int M, int N, int K,
    const float* __restrict__ bias, const float* __restrict__ resid,
    u16* __restrict__ obf, float* __restrict__ of32) {
  __shared__ __align__(16) u16 sA[128 * 64];
  __shared__ __align__(16) u16 sB[128 * 64];
  const int tid  = threadIdx.x;
  const int lane = tid & 63;
  const int wave = tid >> 6;
  const int bm = blockIdx.x * 128;
  const int bn = blockIdx.y * 128;
  const int wm = (wave >> 1) * 64;
  const int wn = (wave & 1) * 64;
  const int lr   = lane & 15;
  const int quad = lane >> 4;

  f32x4 acc[4][4] = {};

  // staging: 1024 slots of 16B per matrix; thread handles slots tid+256*i.
  // slot s -> (row=s>>3, seg'=s&7); fetch global seg = seg' ^ (row&7).
  const u16* gA[4]; const u16* gB[4]; u16* lA[4]; u16* lB[4];
#pragma unroll
  for (int i = 0; i < 4; ++i) {
    const int s   = tid + 256 * i;
    const int row = s >> 3;
    const int seg = (s & 7) ^ (row & 7);
    gA[i] = A  + (size_t)(bm + row) * K + seg * 8;
    gB[i] = Bt + (size_t)(bn + row) * K + seg * 8;
    lA[i] = sA + s * 8;
    lB[i] = sB + s * 8;
  }

  // fragment LDS slot indices (loop-invariant): row r, k-half h, seg h*4+quad
  int ai[4][2], bi[4][2];
#pragma unroll
  for (int mi = 0; mi < 4; ++mi) {
#pragma unroll
    for (int h = 0; h < 2; ++h) {
      const int ra = wm + mi * 16 + lr;
      ai[mi][h] = ra * 8 + ((h * 4 + quad) ^ (ra & 7));
      const int rb = wn + mi * 16 + lr;
      bi[mi][h] = rb * 8 + ((h * 4 + quad) ^ (rb & 7));
    }
  }

  for (int k0 = 0; k0 < K; k0 += 64) {
#pragma unroll
    for (int i = 0; i < 4; ++i) {
      GLD16(gA[i] + k0, lA[i]);
      GLD16(gB[i] + k0, lB[i]);
    }
    __syncthreads();

    const bf16x8* pA = (const bf16x8*)sA;
    const bf16x8* pB = (const bf16x8*)sB;
#pragma unroll
    for (int h = 0; h < 2; ++h) {
      bf16x8 av[4], bv[4];
#pragma unroll
      for (int mi = 0; mi < 4; ++mi) av[mi] = pA[ai[mi][h]];
#pragma unroll
      for (int ni = 0; ni < 4; ++ni) bv[ni] = pB[bi[ni][h]];
#pragma unroll
      for (int mi = 0; mi < 4; ++mi)
#pragma unroll
        for (int ni = 0; ni < 4; ++ni)
          acc[mi][ni] = __builtin_amdgcn_mfma_f32_16x16x32_bf16(
              av[mi], bv[ni], acc[mi][ni], 0, 0, 0);
    }
    __syncthreads();
  }

  // epilogue: C/D layout col=lane&15, row=quad*4+reg (verified m89/m91)
#pragma unroll
  for (int mi = 0; mi < 4; ++mi) {
#pragma unroll
    for (int ni = 0; ni < 4; ++ni) {
      const int col  = bn + wn + ni * 16 + lr;
      const int row0 = bm + wm + mi * 16 + quad * 4;
      if constexpr (EPI == 0) {
        const float bb = bias[col];
#pragma unroll
        for (int r = 0; r < 4; ++r) {
          float v = acc[mi][ni][r] + bb;
          v = fmaxf(v, 0.0f);
          obf[(size_t)(row0 + r) * N + col] = f2bf(v);
        }
      } else {
#pragma unroll
        for (int r = 0; r < 4; ++r) {
          const size_t idx = (size_t)(row0 + r) * N + col;
          of32[idx] = resid[idx] + acc[mi][ni][r];
        }
      }
    }
  }
}

// ---------------------------------------------------------------------------
// Workspace layout (bytes):
//   hcat       [8192 x 3072] bf16              @ 0          (50331648)
//   WcatT      [4096 x 3072] bf16              @ 50331648   (25165824)
//   woT        [1024 x 4096] bf16              @ 75497472   ( 8388608)
//   out1       [8192 x 4096] bf16              @ 83886080   (67108864)
//     bucket_src [262144] i32 (aliases out1)   @ 83886080   ( 1048576)
//     cnt        [16384] i32                   @ 84934656   (   65536)
//     off        [16384] i32                   @ 85000192   (   65536)
//     cursor     [16384] i32                   @ 85065728   (   65536)
// total: 150994944 bytes (144 MB)
// ---------------------------------------------------------------------------
extern "C" void kernel_launch(void* const* d_in, const int* in_sizes, int n_in,
                              void* d_out, int out_size, void* d_ws, size_t ws_size,
                              hipStream_t stream) {
  const float* hs     = (const float*)d_in[0];
  const float* weight = (const float*)d_in[1];   // [2,1024,4096]
  const float* root   = (const float*)d_in[2];   // [1024,4096]
  const float* bias   = (const float*)d_in[3];   // [4096]
  const float* wo     = (const float*)d_in[4];   // [4096,1024]
  const float* gamma  = (const float*)d_in[5];
  const float* beta   = (const float*)d_in[6];
  const int* edge_index = (const int*)d_in[7];   // [2,E]
  const int* edge_type  = (const int*)d_in[8];   // [E]
  float* out = (float*)d_out;

  char* ws = (char*)d_ws;
  u16*   hcat       = (u16*)(ws + 0);
  u16*   WcatT      = (u16*)(ws + 50331648);
  u16*   woT        = (u16*)(ws + 75497472);
  u16*   out1       = (u16*)(ws + 83886080);
  int*   bucket_src = (int*)(ws + 83886080);     // aliases out1 (consumed pre-GEMM1)
  int*   cnt        = (int*)(ws + 84934656);
  int*   off        = (int*)(ws + 85000192);
  int*   cursor     = (int*)(ws + 85065728);

  (void)hipMemsetAsync(cnt, 0, 65536, stream);

  ln_kernel<<<NNODE, 256, 0, stream>>>(hs, gamma, beta, hcat);

  cvt_transpose<<<dim3(FDIM / 32, KCAT / 32), dim3(32, 8), 0, stream>>>(
      weight, root, 2048, KCAT, FDIM, WcatT);
  cvt_transpose<<<dim3(DDIM / 32, FDIM / 32), dim3(32, 8), 0, stream>>>(
      wo, wo, FDIM, FDIM, DDIM, woT);

  count_kernel<<<E_NUM / 256, 256, 0, stream>>>(edge_index, edge_type, cnt);
  scan_kernel<<<1, 1024, 0, stream>>>(cnt, off, cursor);
  fill_kernel<<<E_NUM / 256, 256, 0, stream>>>(edge_index, edge_type, cursor, bucket_src);
  aggregate_kernel<<<NBKT, 256, 0, stream>>>(cnt, off, bucket_src, hcat);

  // out1 = relu([h0|h1|x] @ [W0;W1;root] + bias)   [8192 x 4096] bf16
  gemm_bt<0><<<dim3(8192 / 128, FDIM / 128), 256, 0, stream>>>(
      hcat, WcatT, 8192, FDIM, KCAT, bias, nullptr, out1, nullptr);

  // out = hs + out1 @ wo                            [8192 x 1024] f32
  gemm_bt<1><<<dim3(8192 / 128, DDIM / 128), 256, 0, stream>>>(
      out1, woT, 8192, DDIM, FDIM, nullptr, hs, nullptr, out);
}